// Round 1
// baseline (945.802 us; speedup 1.0000x reference)
//
#include <hip/hip_runtime.h>

constexpr int N = 50000;
constexpr int E = 800000;
constexpr int D = 128;
constexpr int MASKN = 25000;
constexpr int SCAN_CHUNK = 1024;
constexpr int NB_SCAN = (N + SCAN_CHUNK - 1) / SCAN_CHUNK; // 49

// ---------------- CSR build ----------------

__global__ void k_count(const int* __restrict__ src, const int* __restrict__ dst,
                        int* __restrict__ cnt_src, int* __restrict__ cnt_dst) {
    int e = blockIdx.x * blockDim.x + threadIdx.x;
    if (e < E) {
        atomicAdd(&cnt_src[src[e]], 1);
        atomicAdd(&cnt_dst[dst[e]], 1);
    }
}

__global__ void k_scan1(const int* __restrict__ cnt, int* __restrict__ bsum) {
    __shared__ int sh[256];
    int base = blockIdx.x * SCAN_CHUNK;
    int t = threadIdx.x;
    int s = 0;
#pragma unroll
    for (int j = 0; j < 4; ++j) {
        int i = base + t * 4 + j;
        if (i < N) s += cnt[i];
    }
    sh[t] = s;
    __syncthreads();
    for (int o = 128; o > 0; o >>= 1) {
        if (t < o) sh[t] += sh[t + o];
        __syncthreads();
    }
    if (t == 0) bsum[blockIdx.x] = sh[0];
}

__global__ void k_scan2(int* __restrict__ bsum, int* __restrict__ row_ptr) {
    if (threadIdx.x == 0 && blockIdx.x == 0) {
        int run = 0;
        for (int i = 0; i < NB_SCAN; ++i) {
            int v = bsum[i];
            bsum[i] = run;
            run += v;
        }
        row_ptr[N] = run; // == E
    }
}

__global__ void k_scan3(const int* __restrict__ cnt, const int* __restrict__ bsum,
                        int* __restrict__ row_ptr) {
    __shared__ int sh[256];
    int base = blockIdx.x * SCAN_CHUNK;
    int t = threadIdx.x;
    int v[4];
    int tot = 0;
#pragma unroll
    for (int j = 0; j < 4; ++j) {
        int i = base + t * 4 + j;
        v[j] = (i < N) ? cnt[i] : 0;
        tot += v[j];
    }
    sh[t] = tot;
    __syncthreads();
    for (int o = 1; o < 256; o <<= 1) {
        int y = (t >= o) ? sh[t - o] : 0;
        __syncthreads();
        sh[t] += y;
        __syncthreads();
    }
    int excl = sh[t] - tot;
    int off = bsum[blockIdx.x] + excl;
    int run = 0;
#pragma unroll
    for (int j = 0; j < 4; ++j) {
        int i = base + t * 4 + j;
        if (i < N) row_ptr[i] = off + run;
        run += v[j];
    }
}

__global__ void k_fill(const int* __restrict__ src, const int* __restrict__ dst,
                       const int* __restrict__ row_ptr, int* __restrict__ cursor,
                       int* __restrict__ col) {
    int e = blockIdx.x * blockDim.x + threadIdx.x;
    if (e < E) {
        int d = dst[e];
        int p = row_ptr[d] + atomicAdd(&cursor[d], 1);
        col[p] = src[e];
    }
}

__global__ void k_dinv(const int* __restrict__ cs, const int* __restrict__ cd,
                       float* __restrict__ dinv_out, float* __restrict__ dinv_in) {
    int i = blockIdx.x * blockDim.x + threadIdx.x;
    if (i < N) {
        int a = cs[i] > 1 ? cs[i] : 1;
        int b = cd[i] > 1 ? cd[i] : 1;
        dinv_out[i] = rsqrtf((float)a);
        dinv_in[i] = rsqrtf((float)b);
    }
}

__global__ void k_mflag(const int* __restrict__ mask_nodes, int* __restrict__ mflag) {
    int i = blockIdx.x * blockDim.x + threadIdx.x;
    if (i < MASKN) mflag[mask_nodes[i]] = 1;
}

// ---------------- feature prep: masked x scaled by deg_out^-0.5 ----------------

__global__ void k_prep(const float4* __restrict__ x, const float4* __restrict__ tok,
                       const int* __restrict__ mflag, const float* __restrict__ dinv_out,
                       float4* __restrict__ A) {
    int i = blockIdx.x * blockDim.x + threadIdx.x; // over N*32 float4s
    if (i < N * 32) {
        int row = i >> 5;
        int c = i & 31;
        float s = dinv_out[row];
        float4 v = mflag[row] ? tok[c] : x[i];
        A[i] = make_float4(v.x * s, v.y * s, v.z * s, v.w * s);
    }
}

// ---------------- SpMM: B[row] = sum over CSR neighbors of A[col] ----------------
// blockDim = (64,4): one wave per row, float2 per lane.

__global__ void k_spmm(const float2* __restrict__ A, float2* __restrict__ B,
                       const int* __restrict__ row_ptr, const int* __restrict__ col,
                       const int* __restrict__ rows, int nrows) {
    int rr = blockIdx.x * blockDim.y + threadIdx.y;
    if (rr >= nrows) return;
    int row = rows ? rows[rr] : rr;
    int tx = threadIdx.x;
    int beg = row_ptr[row], end = row_ptr[row + 1];
    float2 acc = make_float2(0.f, 0.f);
    for (int e = beg; e < end; ++e) {
        int c = col[e];
        float2 v = A[(size_t)c * 64 + tx];
        acc.x += v.x;
        acc.y += v.y;
    }
    B[(size_t)row * 64 + tx] = acc;
}

// ---------------- fused linear (+degnorm, LN, PReLU) ----------------
// thread t holds W[t,:] in 128 VGPRs; input row broadcast from LDS.

template <bool SCALE_OUT>
__launch_bounds__(128, 2)
__global__ void k_enc(const float* __restrict__ in, float* __restrict__ out,
                      const float* __restrict__ W, const float* __restrict__ bias,
                      const float* __restrict__ g, const float* __restrict__ be,
                      const float* __restrict__ aP, const float* __restrict__ dinv_in,
                      const float* __restrict__ dinv_out) {
    __shared__ float sh[D];
    __shared__ float red[4];
    int t = threadIdx.x;
    float4 w[32];
    const float4* W4 = (const float4*)(W + t * D);
#pragma unroll
    for (int k = 0; k < 32; ++k) w[k] = W4[k];
    float bt = bias[t], gt = g[t], bet = be[t];
    float alpha = aP[0];

    for (int row = blockIdx.x; row < N; row += gridDim.x) {
        sh[t] = in[(size_t)row * D + t];
        __syncthreads();
        const float4* sh4 = (const float4*)sh;
        float acc = 0.f;
#pragma unroll
        for (int k = 0; k < 32; ++k) {
            float4 h = sh4[k];
            acc += w[k].x * h.x + w[k].y * h.y + w[k].z * h.z + w[k].w * h.w;
        }
        float val = (acc + bt) * dinv_in[row];
        // LayerNorm across 128 outputs (2 waves)
        float s = val, q = val * val;
#pragma unroll
        for (int o = 32; o > 0; o >>= 1) {
            s += __shfl_xor(s, o);
            q += __shfl_xor(q, o);
        }
        if ((t & 63) == 0) {
            red[(t >> 6) * 2] = s;
            red[(t >> 6) * 2 + 1] = q;
        }
        __syncthreads();
        float S = red[0] + red[2], Q = red[1] + red[3];
        float mu = S * (1.f / D);
        float var = Q * (1.f / D) - mu * mu;
        float y = (val - mu) * rsqrtf(var + 1e-5f) * gt + bet;
        y = y >= 0.f ? y : alpha * y;
        if (SCALE_OUT) y *= dinv_out[row];
        out[(size_t)row * D + t] = y;
        __syncthreads();
    }
}

// rep = h2 @ We2d^T, zero masked rows, scale by deg_out^-0.5
__launch_bounds__(128, 2)
__global__ void k_rep(const float* __restrict__ in, float* __restrict__ out,
                      const float* __restrict__ W, const int* __restrict__ mflag,
                      const float* __restrict__ dinv_out) {
    __shared__ float sh[D];
    int t = threadIdx.x;
    float4 w[32];
    const float4* W4 = (const float4*)(W + t * D);
#pragma unroll
    for (int k = 0; k < 32; ++k) w[k] = W4[k];
    for (int row = blockIdx.x; row < N; row += gridDim.x) {
        if (mflag[row]) { // uniform per block
            out[(size_t)row * D + t] = 0.f;
            continue;
        }
        sh[t] = in[(size_t)row * D + t];
        __syncthreads();
        const float4* sh4 = (const float4*)sh;
        float acc = 0.f;
#pragma unroll
        for (int k = 0; k < 32; ++k) {
            float4 h = sh4[k];
            acc += w[k].x * h.x + w[k].y * h.y + w[k].z * h.z + w[k].w * h.w;
        }
        out[(size_t)row * D + t] = acc * dinv_out[row];
        __syncthreads();
    }
}

// final linear + degnorm + SCE loss over masked rows
__launch_bounds__(128, 2)
__global__ void k_loss(const float* __restrict__ agg, const float* __restrict__ x,
                       const float* __restrict__ Wd, const float* __restrict__ bd,
                       const float* __restrict__ dinv_in, const int* __restrict__ mask_nodes,
                       float* __restrict__ outp) {
    __shared__ float sh[D];
    __shared__ float red[6];
    int t = threadIdx.x;
    float4 w[32];
    const float4* W4 = (const float4*)(Wd + t * D);
#pragma unroll
    for (int k = 0; k < 32; ++k) w[k] = W4[k];
    float bt = bd[t];
    float block_acc = 0.f;
    for (int idx = blockIdx.x; idx < MASKN; idx += gridDim.x) {
        int m = mask_nodes[idx];
        sh[t] = agg[(size_t)m * D + t];
        __syncthreads();
        const float4* sh4 = (const float4*)sh;
        float acc = 0.f;
#pragma unroll
        for (int k = 0; k < 32; ++k) {
            float4 h = sh4[k];
            acc += w[k].x * h.x + w[k].y * h.y + w[k].z * h.z + w[k].w * h.w;
        }
        float r = (acc + bt) * dinv_in[m];
        float xv = x[(size_t)m * D + t];
        float a = r * r, b = xv * xv, c = r * xv;
#pragma unroll
        for (int o = 32; o > 0; o >>= 1) {
            a += __shfl_xor(a, o);
            b += __shfl_xor(b, o);
            c += __shfl_xor(c, o);
        }
        if ((t & 63) == 0) {
            int wv = t >> 6;
            red[wv * 3] = a;
            red[wv * 3 + 1] = b;
            red[wv * 3 + 2] = c;
        }
        __syncthreads();
        float A_ = red[0] + red[3], B_ = red[1] + red[4], C_ = red[2] + red[5];
        float nr = fmaxf(sqrtf(A_), 1e-12f);
        float nx = fmaxf(sqrtf(B_), 1e-12f);
        float dot = C_ / (nr * nx);
        float term = 1.f - dot;
        block_acc += term * term;
        __syncthreads();
    }
    if (t == 0) atomicAdd(outp, block_acc * (1.f / MASKN));
}

// ---------------- launch ----------------

extern "C" void kernel_launch(void* const* d_in, const int* in_sizes, int n_in,
                              void* d_out, int out_size, void* d_ws, size_t ws_size,
                              hipStream_t stream) {
    const float* x = (const float*)d_in[0];
    const float* tok = (const float*)d_in[1];
    const float* W1 = (const float*)d_in[2];
    const float* b1 = (const float*)d_in[3];
    const float* g1 = (const float*)d_in[4];
    const float* be1 = (const float*)d_in[5];
    const float* a1 = (const float*)d_in[6];
    const float* W2 = (const float*)d_in[7];
    const float* b2 = (const float*)d_in[8];
    const float* g2 = (const float*)d_in[9];
    const float* be2 = (const float*)d_in[10];
    const float* a2 = (const float*)d_in[11];
    const float* We2d = (const float*)d_in[12];
    const float* Wd = (const float*)d_in[13];
    const float* bd = (const float*)d_in[14];
    const int* src = (const int*)d_in[15];
    const int* dst = (const int*)d_in[16];
    const int* mask_nodes = (const int*)d_in[17];

    char* w = (char*)d_ws;
    float* A = (float*)w;       w += (size_t)N * D * 4;
    float* Bf = (float*)w;      w += (size_t)N * D * 4;
    int* col = (int*)w;         w += (size_t)E * 4;
    int* row_ptr = (int*)w;     w += (size_t)(N + 1) * 4;
    int* cnt_src = (int*)w;     w += (size_t)N * 4;
    int* cnt_dst = (int*)w;     w += (size_t)N * 4;
    int* cursor = (int*)w;      w += (size_t)N * 4;
    int* mflag = (int*)w;       w += (size_t)N * 4;
    int* bsum = (int*)w;        w += 256 * 4;
    float* dinv_out = (float*)w; w += (size_t)N * 4;
    float* dinv_in = (float*)w;  w += (size_t)N * 4;

    // zero: cnt_src, cnt_dst, cursor, mflag (contiguous 4*N ints) + output scalar
    hipMemsetAsync(cnt_src, 0, (size_t)4 * N * 4, stream);
    hipMemsetAsync(d_out, 0, sizeof(float), stream);

    k_count<<<(E + 255) / 256, 256, 0, stream>>>(src, dst, cnt_src, cnt_dst);
    k_scan1<<<NB_SCAN, 256, 0, stream>>>(cnt_dst, bsum);
    k_scan2<<<1, 64, 0, stream>>>(bsum, row_ptr);
    k_scan3<<<NB_SCAN, 256, 0, stream>>>(cnt_dst, bsum, row_ptr);
    k_fill<<<(E + 255) / 256, 256, 0, stream>>>(src, dst, row_ptr, cursor, col);
    k_dinv<<<(N + 255) / 256, 256, 0, stream>>>(cnt_src, cnt_dst, dinv_out, dinv_in);
    k_mflag<<<(MASKN + 255) / 256, 256, 0, stream>>>(mask_nodes, mflag);
    k_prep<<<(N * 32 + 255) / 256, 256, 0, stream>>>((const float4*)x, (const float4*)tok,
                                                     mflag, dinv_out, (float4*)A);
    dim3 bs(64, 4);
    // conv1: agg
    k_spmm<<<(N + 3) / 4, bs, 0, stream>>>((const float2*)A, (float2*)Bf, row_ptr, col, nullptr, N);
    // conv1: fc + in-deg norm + LN + PReLU, pre-scale by deg_out^-0.5 for conv2
    k_enc<true><<<512, 128, 0, stream>>>(Bf, A, W1, b1, g1, be1, a1, dinv_in, dinv_out);
    // conv2: agg
    k_spmm<<<(N + 3) / 4, bs, 0, stream>>>((const float2*)A, (float2*)Bf, row_ptr, col, nullptr, N);
    // conv2 epilogue: h2 (unscaled)
    k_enc<false><<<512, 128, 0, stream>>>(Bf, A, W2, b2, g2, be2, a2, dinv_in, dinv_out);
    // encoder_to_decoder + re-mask + pre-scale for conv3
    k_rep<<<512, 128, 0, stream>>>(A, Bf, We2d, mflag, dinv_out);
    // conv3: agg, masked rows only
    k_spmm<<<(MASKN + 3) / 4, bs, 0, stream>>>((const float2*)Bf, (float2*)A, row_ptr, col,
                                               mask_nodes, MASKN);
    // decoder fc + SCE loss
    k_loss<<<512, 128, 0, stream>>>(A, x, Wd, bd, dinv_in, mask_nodes, (float*)d_out);
}